// Round 5
// baseline (649.495 us; speedup 1.0000x reference)
//
#include <hip/hip_runtime.h>
#include <hip/hip_bf16.h>
#include <cstdint>

#define HIDDEN 1024
#define HEADS 16
#define HDIM 64
#define BATCH 2
#define SEQ 2048

typedef __attribute__((ext_vector_type(8))) short bfrag;   // 8 bf16 (4 VGPRs)
typedef __attribute__((ext_vector_type(4))) short bhalf4;  // 4 bf16 (2 VGPRs)
typedef __attribute__((ext_vector_type(4))) float f32x4;   // MFMA C/D

union U4B { uint4 u; bfrag b; };
union U2B { uint2 u; bhalf4 b; };

#if defined(__has_builtin)
#if __has_builtin(__builtin_amdgcn_mfma_f32_16x16x16bf16_1k)
#define MFMA16(a, b, c) __builtin_amdgcn_mfma_f32_16x16x16bf16_1k(a, b, c, 0, 0, 0)
#elif __has_builtin(__builtin_amdgcn_mfma_f32_16x16x16_bf16)
#define MFMA16(a, b, c) __builtin_amdgcn_mfma_f32_16x16x16_bf16(a, b, c, 0, 0, 0)
#endif
#endif

// round-to-nearest-even f32 -> bf16 bits
__device__ inline unsigned short f2bf(float f) {
  unsigned u = __float_as_uint(f);
  return (unsigned short)((u + 0x7FFFu + ((u >> 16) & 1u)) >> 16);
}
// Ootomo split: f ~= hi + lo
__device__ inline void split2(float f, unsigned short& h, unsigned short& l) {
  unsigned u = __float_as_uint(f);
  unsigned hb = (u + 0x7FFFu + ((u >> 16) & 1u)) & 0xFFFF0000u;
  h = (unsigned short)(hb >> 16);
  l = f2bf(f - __uint_as_float(hb));
}
__device__ inline unsigned cvt_pk_bf16(float a, float b) {
  unsigned d;
  asm("v_cvt_pk_bf16_f32 %0, %1, %2" : "=v"(d) : "v"(a), "v"(b));
  return d;
}
// async global->LDS 16B per lane; LDS dst wave-uniform base + lane*16
__device__ inline void gll16(const void* g, void* l) {
  __builtin_amdgcn_global_load_lds(
      (const __attribute__((address_space(1))) void*)g,
      (__attribute__((address_space(3))) void*)l, 16, 0, 0);
}

// ---------------- RoPE cos/sin tables: [S][32] each ----------------
__global__ __launch_bounds__(256) void rope_table_k(float* __restrict__ ctab,
                                                    float* __restrict__ stab) {
  int idx = blockIdx.x * 256 + threadIdx.x;
  int s = idx >> 5, i = idx & 31;
  float inv = powf(10000.0f, -(float)i / 32.0f);
  float a = (float)s * inv;
  ctab[idx] = cosf(a);
  stab[idx] = sinf(a);
}

// ---- split fp32 [R][1024] -> bf16 hi/lo planes, pre-swizzled for BK=32 ----
// granule g (8 elems) of row r stored at position (g&~3) | ((g&3)^(r&3)^((r>>2)&3))
__global__ __launch_bounds__(256) void split_swz4(const float* __restrict__ in,
                                                  ushort* __restrict__ ph,
                                                  ushort* __restrict__ pl) {
  int gid = blockIdx.x * 256 + threadIdx.x;   // one 8-elem granule each
  int r = gid >> 7, g = gid & 127;
  const float* p = in + (size_t)r * 1024 + g * 8;
  float4 a = *(const float4*)p, b = *(const float4*)(p + 4);
  float v[8] = {a.x, a.y, a.z, a.w, b.x, b.y, b.z, b.w};
  unsigned hw[4], lw[4];
#pragma unroll
  for (int i = 0; i < 4; i++) {
    unsigned short h0, l0, h1, l1;
    split2(v[2 * i], h0, l0);
    split2(v[2 * i + 1], h1, l1);
    hw[i] = (unsigned)h0 | ((unsigned)h1 << 16);
    lw[i] = (unsigned)l0 | ((unsigned)l1 << 16);
  }
  size_t dst = (size_t)r * 1024 + (g >> 2) * 32 +
               ((((g & 3) ^ (r & 3) ^ ((r >> 2) & 3))) << 3);
  *(uint4*)(ph + dst) = make_uint4(hw[0], hw[1], hw[2], hw[3]);
  *(uint4*)(pl + dst) = make_uint4(lw[0], lw[1], lw[2], lw[3]);
}

// ---------------- pre-split MFMA GEMM, BK=32, global_load_lds ----------------
// C = A @ B^T + bias from pre-swizzled planes. 128x128 tile, 4 waves (2x2),
// 4x4 16x16x32 frags, bf16x3: acc += ah*bh + ah*bl + al*bh.
__global__ __launch_bounds__(256, 3) void gemm32(
    const ushort* __restrict__ aph, const ushort* __restrict__ apl,
    const ushort* __restrict__ bph, const ushort* __restrict__ bpl,
    const float* __restrict__ bias, float* __restrict__ Cout,
    float* __restrict__ Qb, float* __restrict__ Kb, float* __restrict__ Vb,
    int N, int mode) {
  __shared__ __align__(16) ushort Ah[128 * 32], Al[128 * 32];
  __shared__ __align__(16) ushort Bh[128 * 32], Bl[128 * 32];
  const int t = threadIdx.x, lane = t & 63, w = t >> 6;
  const int wm = w >> 1, wn = w & 1, fr = lane & 15, fg = lane >> 4;
  const int n0 = blockIdx.x * 128, m0 = blockIdx.y * 128;

  f32x4 acc[4][4];
#pragma unroll
  for (int i = 0; i < 4; i++)
#pragma unroll
    for (int j = 0; j < 4; j++) acc[i][j] = (f32x4){0.f, 0.f, 0.f, 0.f};

  // wave w stages one plane: 128 rows x 32 ushorts = 8KB = 8 x gll16
  const ushort* pl4 = (w == 0) ? aph : (w == 1) ? apl : (w == 2) ? bph : bpl;
  ushort* ld4 = (w == 0) ? Ah : (w == 1) ? Al : (w == 2) ? Bh : Bl;
  const int rb = (w < 2) ? m0 : n0;

  for (int kt = 0; kt < 1024; kt += 32) {
    __syncthreads();   // previous tile consumed
#pragma unroll
    for (int i = 0; i < 8; i++) {
      const ushort* src = pl4 + (size_t)(rb + i * 16 + (lane >> 2)) * 1024 +
                          kt + ((lane & 3) << 3);
      gll16(src, &ld4[i * 512]);
    }
    __syncthreads();   // compiler drains vmcnt before barrier

    bfrag ah[4], al[4];
#pragma unroll
    for (int i = 0; i < 4; i++) {
      int r = wm * 64 + i * 16 + fr;
      int ad = r * 32 + ((fg ^ (r & 3) ^ ((r >> 2) & 3)) << 3);
      ah[i] = *(const bfrag*)&Ah[ad];
      al[i] = *(const bfrag*)&Al[ad];
    }
#pragma unroll
    for (int j = 0; j < 4; j++) {
      int r = wn * 64 + j * 16 + fr;
      int ad = r * 32 + ((fg ^ (r & 3) ^ ((r >> 2) & 3)) << 3);
      bfrag bh = *(const bfrag*)&Bh[ad];
      bfrag bl = *(const bfrag*)&Bl[ad];
#pragma unroll
      for (int i = 0; i < 4; i++) {
        acc[i][j] = __builtin_amdgcn_mfma_f32_16x16x32_bf16(ah[i], bh, acc[i][j], 0, 0, 0);
        acc[i][j] = __builtin_amdgcn_mfma_f32_16x16x32_bf16(ah[i], bl, acc[i][j], 0, 0, 0);
        acc[i][j] = __builtin_amdgcn_mfma_f32_16x16x32_bf16(al[i], bh, acc[i][j], 0, 0, 0);
      }
    }
  }

  // epilogue: C/D col = fr, row = fg*4 + reg
#pragma unroll
  for (int j = 0; j < 4; j++) {
    const int n = n0 + wn * 64 + j * 16 + fr;
    const float bb = bias[n];
#pragma unroll
    for (int i = 0; i < 4; i++) {
#pragma unroll
      for (int reg = 0; reg < 4; reg++) {
        const int m = m0 + wm * 64 + i * 16 + fg * 4 + reg;
        const float val = acc[i][j][reg] + bb;
        if (mode == 0) {
          Cout[(size_t)m * N + n] = val;
        } else {
          const int which = n >> 10;
          const int h = (n >> 6) & (HEADS - 1);
          const int d = n & (HDIM - 1);
          const int b = m >> 11, s = m & (SEQ - 1);
          float* base = (which == 0) ? Qb : ((which == 1) ? Kb : Vb);
          base[(((size_t)(b * HEADS + h)) * SEQ + s) * HDIM + d] = val;
        }
      }
    }
  }
}

// ---- RoPE + split: Q planes linear (scaled 1/8), K planes swizzled ----
__global__ __launch_bounds__(256) void rope_split_k(
    const float* __restrict__ Qb, const float* __restrict__ Kb,
    const float* __restrict__ ctab, const float* __restrict__ stab,
    ushort* __restrict__ Qh, ushort* __restrict__ Ql,
    ushort* __restrict__ Kh, ushort* __restrict__ Kl) {
  int idx = blockIdx.x * 256 + threadIdx.x;   // row*4 + dq
  int row = idx >> 2, dq = idx & 3;
  int d0 = dq * 8;
  int s = row & (SEQ - 1);
  const bool isQ = (blockIdx.y == 0);
  const float* P = (isQ ? Qb : Kb) + (size_t)row * 64;
  float4 a0 = *(const float4*)(P + d0), a1 = *(const float4*)(P + d0 + 4);
  float4 b0 = *(const float4*)(P + d0 + 32), b1 = *(const float4*)(P + d0 + 36);
  float4 c0 = *(const float4*)(ctab + s * 32 + d0), c1 = *(const float4*)(ctab + s * 32 + d0 + 4);
  float4 s0 = *(const float4*)(stab + s * 32 + d0), s1 = *(const float4*)(stab + s * 32 + d0 + 4);
  float lo[8] = {a0.x, a0.y, a0.z, a0.w, a1.x, a1.y, a1.z, a1.w};
  float hi[8] = {b0.x, b0.y, b0.z, b0.w, b1.x, b1.y, b1.z, b1.w};
  float cc[8] = {c0.x, c0.y, c0.z, c0.w, c1.x, c1.y, c1.z, c1.w};
  float ss[8] = {s0.x, s0.y, s0.z, s0.w, s1.x, s1.y, s1.z, s1.w};
  const float sc = isQ ? 0.125f : 1.0f;
  unsigned lh[4], ll[4], hh[4], hl[4];
#pragma unroll
  for (int i = 0; i < 4; i++) {
    float n0a = (lo[2 * i] * cc[2 * i] - hi[2 * i] * ss[2 * i]) * sc;
    float n0b = (lo[2 * i + 1] * cc[2 * i + 1] - hi[2 * i + 1] * ss[2 * i + 1]) * sc;
    float n1a = (hi[2 * i] * cc[2 * i] + lo[2 * i] * ss[2 * i]) * sc;
    float n1b = (hi[2 * i + 1] * cc[2 * i + 1] + lo[2 * i + 1] * ss[2 * i + 1]) * sc;
    unsigned short x0, y0, x1, y1;
    split2(n0a, x0, y0); split2(n0b, x1, y1);
    lh[i] = (unsigned)x0 | ((unsigned)x1 << 16);
    ll[i] = (unsigned)y0 | ((unsigned)y1 << 16);
    split2(n1a, x0, y0); split2(n1b, x1, y1);
    hh[i] = (unsigned)x0 | ((unsigned)x1 << 16);
    hl[i] = (unsigned)y0 | ((unsigned)y1 << 16);
  }
  size_t base = (size_t)row * 64;
  if (isQ) {
    *(uint4*)(Qh + base + d0) = make_uint4(lh[0], lh[1], lh[2], lh[3]);
    *(uint4*)(Ql + base + d0) = make_uint4(ll[0], ll[1], ll[2], ll[3]);
    *(uint4*)(Qh + base + d0 + 32) = make_uint4(hh[0], hh[1], hh[2], hh[3]);
    *(uint4*)(Ql + base + d0 + 32) = make_uint4(hl[0], hl[1], hl[2], hl[3]);
  } else {
    int glo = (dq ^ (s & 7)) << 3;
    int ghi = ((dq + 4) ^ (s & 7)) << 3;
    *(uint4*)(Kh + base + glo) = make_uint4(lh[0], lh[1], lh[2], lh[3]);
    *(uint4*)(Kl + base + glo) = make_uint4(ll[0], ll[1], ll[2], ll[3]);
    *(uint4*)(Kh + base + ghi) = make_uint4(hh[0], hh[1], hh[2], hh[3]);
    *(uint4*)(Kl + base + ghi) = make_uint4(hl[0], hl[1], hl[2], hl[3]);
  }
}

// ---- V transpose+split: Vb[bh][s][d] -> Vt planes [(bh*64+d)][s swizzled] ----
__global__ __launch_bounds__(256) void vtrans_split(const float* __restrict__ Vb,
                                                    ushort* __restrict__ Vth,
                                                    ushort* __restrict__ Vtl) {
  __shared__ float ftile[64][65];
  const int t = threadIdx.x;
  const int kt = blockIdx.x, bh = blockIdx.y;   // kt: 64-key tile
  {
    int s_loc = t >> 2, dc = (t & 3) * 16;
    const float* p = Vb + ((size_t)(bh * SEQ) + kt * 64 + s_loc) * 64 + dc;
#pragma unroll
    for (int j = 0; j < 4; j++) {
      float4 v = *(const float4*)(p + j * 4);
      ftile[s_loc][dc + j * 4 + 0] = v.x;
      ftile[s_loc][dc + j * 4 + 1] = v.y;
      ftile[s_loc][dc + j * 4 + 2] = v.z;
      ftile[s_loc][dc + j * 4 + 3] = v.w;
    }
  }
  __syncthreads();
  int d = t >> 2, sc = (t & 3) * 16;
  size_t rowb = ((size_t)(bh * 64 + d)) * SEQ + kt * 64;
#pragma unroll
  for (int jg = 0; jg < 2; jg++) {
    unsigned hw[4], lw[4];
#pragma unroll
    for (int i = 0; i < 4; i++) {
      unsigned short h0, l0, h1, l1;
      split2(ftile[sc + jg * 8 + 2 * i][d], h0, l0);
      split2(ftile[sc + jg * 8 + 2 * i + 1][d], h1, l1);
      hw[i] = (unsigned)h0 | ((unsigned)h1 << 16);
      lw[i] = (unsigned)l0 | ((unsigned)l1 << 16);
    }
    int gsrc = ((sc >> 3) + jg) & 7;
    int swz = (gsrc ^ (d & 7) ^ ((d >> 3) & 7)) << 3;
    *(uint4*)(Vth + rowb + swz) = make_uint4(hw[0], hw[1], hw[2], hw[3]);
    *(uint4*)(Vtl + rowb + swz) = make_uint4(lw[0], lw[1], lw[2], lw[3]);
  }
}

// ---------------- MFMA flash attention, bf16x3, pre-split inputs ----------------
// 4 waves, Q-block 128 (32/wave), K-tile 64. Staging = global_load_lds only.
// Swapped QK^T (lane owns q=fr scores); PV via 16x16x16 MFMA: the swapped
// D-layout (key = ki*16+4fg+r) IS the x16 A-layout (k = 4fg+e, step ki) ->
// P feeds PV lane-locally, zero cross-lane ops.
__global__ __launch_bounds__(256, 3) void attn_mfma2(
    const ushort* __restrict__ Qh, const ushort* __restrict__ Ql,
    const ushort* __restrict__ Kh, const ushort* __restrict__ Kl,
    const ushort* __restrict__ Vth, const ushort* __restrict__ Vtl,
    float* __restrict__ Ab) {
  __shared__ __align__(16) ushort Ks_h[64 * 64], Ks_l[64 * 64];
  __shared__ __align__(16) ushort Vs_h[64 * 64], Vs_l[64 * 64];

  const int t = threadIdx.x, lane = t & 63, w = t >> 6;
  const int fr = lane & 15, fg = lane >> 4;
  const int q0 = blockIdx.x * 128;
  const int h = blockIdx.y, b = blockIdx.z;
  const int bh = b * HEADS + h;

  // Q fragments from pre-split planes (linear)
  bfrag qh[2][2], ql[2][2];
#pragma unroll
  for (int qf = 0; qf < 2; qf++)
#pragma unroll
    for (int kk = 0; kk < 2; kk++) {
      size_t off = ((size_t)bh * SEQ + q0 + w * 32 + qf * 16 + fr) * 64 + kk * 32 + fg * 8;
      U4B uh, ul;
      uh.u = *(const uint4*)(Qh + off);
      ul.u = *(const uint4*)(Ql + off);
      qh[qf][kk] = uh.b;
      ql[qf][kk] = ul.b;
    }

  f32x4 Oacc[2][4];
#pragma unroll
  for (int qf = 0; qf < 2; qf++)
#pragma unroll
    for (int df = 0; df < 4; df++) Oacc[qf][df] = (f32x4){0.f, 0.f, 0.f, 0.f};
  float m_i[2] = {-1e30f, -1e30f}, l_i[2] = {0.f, 0.f};

  const int srcA = fr + ((fg & 1) << 5);   // (fallback path only)
  const int kisel = fg >> 1;

  for (int kt = 0; kt < SEQ; kt += 64) {
    __syncthreads();   // previous tile consumed
    // wave w stages one plane (8 x 1KB)
    if (w < 2) {
      const ushort* p = w ? Kl : Kh;
      ushort* ld = w ? Ks_l : Ks_h;
#pragma unroll
      for (int i = 0; i < 8; i++) {
        const ushort* src = p + ((size_t)bh * SEQ + kt + i * 8 + (lane >> 3)) * 64 + ((lane & 7) << 3);
        gll16(src, &ld[i * 512]);
      }
    } else {
      const ushort* p = (w == 3) ? Vtl : Vth;
      ushort* ld = (w == 3) ? Vs_l : Vs_h;
#pragma unroll
      for (int i = 0; i < 8; i++) {
        const ushort* src = p + ((size_t)(bh * 64) + i * 8 + (lane >> 3)) * SEQ + kt + ((lane & 7) << 3);
        gll16(src, &ld[i * 512]);
      }
    }
    __syncthreads();   // vmcnt drained by compiler

    // QK^T swapped: sacc[ki][qf]: key = 16ki + 4fg + r, q = 16qf + fr
    f32x4 sacc[4][2];
#pragma unroll
    for (int ki = 0; ki < 4; ki++)
#pragma unroll
      for (int qf = 0; qf < 2; qf++) sacc[ki][qf] = (f32x4){0.f, 0.f, 0.f, 0.f};
#pragma unroll
    for (int kk = 0; kk < 2; kk++) {
#pragma unroll
      for (int ki = 0; ki < 4; ki++) {
        int r = ki * 16 + fr;
        int ad = r * 64 + (((kk * 4 + fg) ^ (r & 7)) << 3);
        bfrag kh = *(const bfrag*)&Ks_h[ad];
        bfrag kl = *(const bfrag*)&Ks_l[ad];
#pragma unroll
        for (int qf = 0; qf < 2; qf++) {
          sacc[ki][qf] = __builtin_amdgcn_mfma_f32_16x16x32_bf16(kh, qh[qf][kk], sacc[ki][qf], 0, 0, 0);
          sacc[ki][qf] = __builtin_amdgcn_mfma_f32_16x16x32_bf16(kh, ql[qf][kk], sacc[ki][qf], 0, 0, 0);
          sacc[ki][qf] = __builtin_amdgcn_mfma_f32_16x16x32_bf16(kl, qh[qf][kk], sacc[ki][qf], 0, 0, 0);
        }
      }
    }

#ifdef MFMA16
    bhalf4 paH[2][4], paL[2][4];   // [qf][ki] x16 A-frags (lane-local P)
#else
    unsigned phv[2][2][4], plv[2][2][4];   // [qf][pair][ki]
#endif
    // online softmax; lane's q = qf*16 + fr
#pragma unroll
    for (int qf = 0; qf < 2; qf++) {
      float mm = -1e30f;
#pragma unroll
      for (int ki = 0; ki < 4; ki++)
#pragma unroll
        for (int r = 0; r < 4; r++) mm = fmaxf(mm, sacc[ki][qf][r]);
      mm = fmaxf(mm, __shfl_xor(mm, 16));
      mm = fmaxf(mm, __shfl_xor(mm, 32));
      float mn = fmaxf(m_i[qf], mm);
      float alpha = __expf(m_i[qf] - mn);
      m_i[qf] = mn;
      float rs = 0.f;
      float pv[4][4];
#pragma unroll
      for (int ki = 0; ki < 4; ki++)
#pragma unroll
        for (int r = 0; r < 4; r++) {
          float p = __expf(sacc[ki][qf][r] - mn);
          pv[ki][r] = p;
          rs += p;
        }
      rs += __shfl_xor(rs, 16);
      rs += __shfl_xor(rs, 32);
      l_i[qf] = l_i[qf] * alpha + rs;
#ifdef MFMA16
#pragma unroll
      for (int ki = 0; ki < 4; ki++) {
        unsigned h0 = cvt_pk_bf16(pv[ki][0], pv[ki][1]);
        unsigned h1 = cvt_pk_bf16(pv[ki][2], pv[ki][3]);
        float e00 = __uint_as_float(h0 << 16), e01 = __uint_as_float(h0 & 0xFFFF0000u);
        float e10 = __uint_as_float(h1 << 16), e11 = __uint_as_float(h1 & 0xFFFF0000u);
        unsigned l0 = cvt_pk_bf16(pv[ki][0] - e00, pv[ki][1] - e01);
        unsigned l1 = cvt_pk_bf16(pv[ki][2] - e10, pv[ki][3] - e11);
        U2B th, tl;
        th.u = make_uint2(h0, h1);
        tl.u = make_uint2(l0, l1);
        paH[qf][ki] = th.b;
        paL[qf][ki] = tl.b;
      }
#else
#pragma unroll
      for (int ki = 0; ki < 4; ki++)
#pragma unroll
        for (int pr = 0; pr < 2; pr++) {
          float p0 = pv[ki][2 * pr], p1 = pv[ki][2 * pr + 1];
          unsigned hp = cvt_pk_bf16(p0, p1);
          float h0 = __uint_as_float(hp << 16);
          float h1 = __uint_as_float(hp & 0xFFFF0000u);
          phv[qf][pr][ki] = hp;
          plv[qf][pr][ki] = cvt_pk_bf16(p0 - h0, p1 - h1);
        }
#endif
      // rescale Oacc rows (their q = 16qf + 4fg + reg)
      float ar[4];
#pragma unroll
      for (int r = 0; r < 4; r++) ar[r] = __shfl(alpha, 4 * fg + r);
#pragma unroll
      for (int df = 0; df < 4; df++)
#pragma unroll
        for (int r = 0; r < 4; r++) Oacc[qf][df][r] *= ar[r];
    }

#ifdef MFMA16
    // PV via 16x16x16: step ki covers keys ki*16..+15; A = own packed P;
    // B = Vs[d = df*16+fr][keys ki*16 + 4fg + 0..3] (b64, swizzle-derived)
#pragma unroll
    for (int ki = 0; ki < 4; ki++) {
      bhalf4 vh[4], vl[4];
#pragma unroll
      for (int df = 0; df < 4; df++) {
        int d = df * 16 + fr;
        int ad = d * 64 + ((((2 * ki + (fg >> 1)) ^ (d & 7) ^ ((d >> 3) & 7))) << 3) + ((fg & 1) << 2);
        vh[df] = *(const bhalf4*)&Vs_h[ad];
        vl[df] = *(const bhalf4*)&Vs_l[ad];
      }
#pragma unroll
      for (int qf = 0; qf < 2; qf++)
#pragma unroll
        for (int df = 0; df < 4; df++) {
          Oacc[qf][df] = MFMA16(paH[qf][ki], vh[df], Oacc[qf][df]);
          Oacc[qf][df] = MFMA16(paH[qf][ki], vl[df], Oacc[qf][df]);
          Oacc[qf][df] = MFMA16(paL[qf][ki], vh[df], Oacc[qf][df]);
        }
    }
#else
    // Fallback PV via 16x16x32 + shfl regather of P fragments
#pragma unroll
    for (int kk = 0; kk < 2; kk++) {
      bfrag vh[4], vl[4];
#pragma unroll
      for (int df = 0; df < 4; df++) {
        int d = df * 16 + fr;
        int ad = d * 64 + (((kk * 4 + fg) ^ (d & 7) ^ ((d >> 3) & 7)) << 3);
        vh[df] = *(const bfrag*)&Vs_h[ad];
        vl[df] = *(const bfrag*)&Vs_l[ad];
      }
#pragma unroll
      for (int qf = 0; qf < 2; qf++) {
        U4B pah, pal;
#pragma unroll
        for (int wd = 0; wd < 4; wd++) {
          int src = srcA + ((wd >> 1) << 4);
          int pr = wd & 1;
          unsigned a0 = (unsigned)__shfl((int)phv[qf][pr][2 * kk], src);
          unsigned a1 = (unsigned)__shfl((int)phv[qf][pr][2 * kk + 1], src);
          unsigned b0 = (unsigned)__shfl((int)plv[qf][pr][2 * kk], src);
          unsigned b1 = (unsigned)__shfl((int)plv[qf][pr][2 * kk + 1], src);
          (&pah.u.x)[wd] = kisel ? a1 : a0;
          (&pal.u.x)[wd] = kisel ? b1 : b0;
        }
#pragma unroll
        for (int df = 0; df < 4; df++) {
          Oacc[qf][df] = __builtin_amdgcn_mfma_f32_16x16x32_bf16(pah.b, vh[df], Oacc[qf][df], 0, 0, 0);
          Oacc[qf][df] = __builtin_amdgcn_mfma_f32_16x16x32_bf16(pah.b, vl[df], Oacc[qf][df], 0, 0, 0);
          Oacc[qf][df] = __builtin_amdgcn_mfma_f32_16x16x32_bf16(pal.b, vh[df], Oacc[qf][df], 0, 0, 0);
        }
      }
    }
#endif
  }

  // epilogue: Ab[m][1024], m = b*SEQ+s, col = h*64+d
#pragma unroll
  for (int qf = 0; qf < 2; qf++) {
    float lr[4];
#pragma unroll
    for (int r = 0; r < 4; r++) lr[r] = 1.0f / __shfl(l_i[qf], 4 * fg + r);
#pragma unroll
    for (int df = 0; df < 4; df++)
#pragma unroll
      for (int r = 0; r < 4; r++) {
        int s = q0 + w * 32 + qf * 16 + 4 * fg + r;
        int d = df * 16 + fr;
        Ab[((size_t)(b * SEQ + s)) * 1024 + h * 64 + d] = Oacc[qf][df][r] * lr[r];
      }
  }
}

extern "C" void kernel_launch(void* const* d_in, const int* in_sizes, int n_in,
                              void* d_out, int out_size, void* d_ws, size_t ws_size,
                              hipStream_t stream) {
  const float* x    = (const float*)d_in[0];
  const float* Wqkv = (const float*)d_in[1];
  const float* bqkv = (const float*)d_in[2];
  const float* Wout = (const float*)d_in[3];
  const float* bout = (const float*)d_in[4];
  float* out = (float*)d_out;

  char* W = (char*)d_ws;
  float* ctab = (float*)W;  W += (size_t)SEQ * 32 * 4;
  float* stab = (float*)W;  W += (size_t)SEQ * 32 * 4;
  float* Qb   = (float*)W;  W += (size_t)16 << 20;   // alias: Abf after rope
  float* Kb   = (float*)W;  W += (size_t)16 << 20;   // alias: abh+abl after rope
  float* Vb   = (float*)W;  W += (size_t)16 << 20;
  ushort* xh  = (ushort*)W; W += (size_t)8 << 20;    // alias: Qhp after gemm1
  ushort* xl  = (ushort*)W; W += (size_t)8 << 20;    // alias: Qlp after gemm1
  ushort* wqh = (ushort*)W; W += (size_t)6 << 20;
  ushort* wql = (ushort*)W; W += (size_t)6 << 20;
  ushort* woh = (ushort*)W; W += (size_t)2 << 20;
  ushort* wol = (ushort*)W; W += (size_t)2 << 20;
  ushort* Khp = (ushort*)W; W += (size_t)8 << 20;
  ushort* Klp = (ushort*)W; W += (size_t)8 << 20;
  ushort* Vthp = (ushort*)W; W += (size_t)8 << 20;
  ushort* Vtlp = (ushort*)W; W += (size_t)8 << 20;
  ushort* Qhp = xh;                   // xh/xl dead after gemm1
  ushort* Qlp = xl;
  float* Abf = Qb;                    // Qb fp32 dead after rope_split
  ushort* abh = (ushort*)Kb;          // Kb fp32 dead after rope_split
  ushort* abl = abh + ((size_t)4 << 20);

  hipLaunchKernelGGL(rope_table_k, dim3(SEQ * 32 / 256), dim3(256), 0, stream, ctab, stab);
  hipLaunchKernelGGL(split_swz4, dim3(4096 / 2), dim3(256), 0, stream, x, xh, xl);
  hipLaunchKernelGGL(split_swz4, dim3(3072 / 2), dim3(256), 0, stream, Wqkv, wqh, wql);
  hipLaunchKernelGGL(split_swz4, dim3(1024 / 2), dim3(256), 0, stream, Wout, woh, wol);
  hipLaunchKernelGGL(gemm32, dim3(3072 / 128, 4096 / 128), dim3(256), 0, stream,
                     xh, xl, wqh, wql, bqkv, (float*)nullptr, Qb, Kb, Vb, 3072, 1);
  hipLaunchKernelGGL(rope_split_k, dim3(BATCH * HEADS * SEQ * 4 / 256, 2), dim3(256), 0, stream,
                     Qb, Kb, ctab, stab, Qhp, Qlp, Khp, Klp);
  hipLaunchKernelGGL(vtrans_split, dim3(SEQ / 64, BATCH * HEADS), dim3(256), 0, stream,
                     Vb, Vthp, Vtlp);
  hipLaunchKernelGGL(attn_mfma2, dim3(SEQ / 128, HEADS, BATCH), dim3(256), 0, stream,
                     Qhp, Qlp, Khp, Klp, Vthp, Vtlp, Abf);
  hipLaunchKernelGGL(split_swz4, dim3(4096 / 2), dim3(256), 0, stream, Abf, abh, abl);
  hipLaunchKernelGGL(gemm32, dim3(1024 / 128, 4096 / 128), dim3(256), 0, stream,
                     abh, abl, woh, wol, bout, out,
                     (float*)nullptr, (float*)nullptr, (float*)nullptr, 1024, 0);
}

// Round 6
// 374.726 us; speedup vs baseline: 1.7333x; 1.7333x over previous
//
#include <hip/hip_runtime.h>
#include <hip/hip_bf16.h>
#include <cstdint>

#define HIDDEN 1024
#define HEADS 16
#define HDIM 64
#define BATCH 2
#define SEQ 2048

typedef __attribute__((ext_vector_type(8))) short bfrag;   // 8 bf16 (4 VGPRs)
typedef __attribute__((ext_vector_type(4))) short bhalf4;  // 4 bf16 (2 VGPRs)
typedef __attribute__((ext_vector_type(4))) float f32x4;   // MFMA C/D

union U4B { uint4 u; bfrag b; };
union U2B { uint2 u; bhalf4 b; };

#if defined(__has_builtin)
#if __has_builtin(__builtin_amdgcn_mfma_f32_16x16x16bf16_1k)
#define MFMA16(a, b, c) __builtin_amdgcn_mfma_f32_16x16x16bf16_1k(a, b, c, 0, 0, 0)
#elif __has_builtin(__builtin_amdgcn_mfma_f32_16x16x16_bf16)
#define MFMA16(a, b, c) __builtin_amdgcn_mfma_f32_16x16x16_bf16(a, b, c, 0, 0, 0)
#endif
#endif

// round-to-nearest-even f32 -> bf16 bits
__device__ inline unsigned short f2bf(float f) {
  unsigned u = __float_as_uint(f);
  return (unsigned short)((u + 0x7FFFu + ((u >> 16) & 1u)) >> 16);
}
// Ootomo split: f ~= hi + lo
__device__ inline void split2(float f, unsigned short& h, unsigned short& l) {
  unsigned u = __float_as_uint(f);
  unsigned hb = (u + 0x7FFFu + ((u >> 16) & 1u)) & 0xFFFF0000u;
  h = (unsigned short)(hb >> 16);
  l = f2bf(f - __uint_as_float(hb));
}
__device__ inline unsigned cvt_pk_bf16(float a, float b) {
  unsigned d;
  asm("v_cvt_pk_bf16_f32 %0, %1, %2" : "=v"(d) : "v"(a), "v"(b));
  return d;
}
// async global->LDS 16B per lane; LDS dst wave-uniform base + lane*16
__device__ inline void gll16(const void* g, void* l) {
  __builtin_amdgcn_global_load_lds(
      (const __attribute__((address_space(1))) void*)g,
      (__attribute__((address_space(3))) void*)l, 16, 0, 0);
}

// ---------------- RoPE cos/sin tables: [S][32] each ----------------
__global__ __launch_bounds__(256) void rope_table_k(float* __restrict__ ctab,
                                                    float* __restrict__ stab) {
  int idx = blockIdx.x * 256 + threadIdx.x;
  int s = idx >> 5, i = idx & 31;
  float inv = powf(10000.0f, -(float)i / 32.0f);
  float a = (float)s * inv;
  ctab[idx] = cosf(a);
  stab[idx] = sinf(a);
}

// ---- split fp32 [R][1024] -> bf16 hi/lo planes, pre-swizzled for BK=32 ----
__global__ __launch_bounds__(256) void split_swz4(const float* __restrict__ in,
                                                  ushort* __restrict__ ph,
                                                  ushort* __restrict__ pl) {
  int gid = blockIdx.x * 256 + threadIdx.x;   // one 8-elem granule each
  int r = gid >> 7, g = gid & 127;
  const float* p = in + (size_t)r * 1024 + g * 8;
  float4 a = *(const float4*)p, b = *(const float4*)(p + 4);
  float v[8] = {a.x, a.y, a.z, a.w, b.x, b.y, b.z, b.w};
  unsigned hw[4], lw[4];
#pragma unroll
  for (int i = 0; i < 4; i++) {
    unsigned short h0, l0, h1, l1;
    split2(v[2 * i], h0, l0);
    split2(v[2 * i + 1], h1, l1);
    hw[i] = (unsigned)h0 | ((unsigned)h1 << 16);
    lw[i] = (unsigned)l0 | ((unsigned)l1 << 16);
  }
  size_t dst = (size_t)r * 1024 + (g >> 2) * 32 +
               ((((g & 3) ^ (r & 3) ^ ((r >> 2) & 3))) << 3);
  *(uint4*)(ph + dst) = make_uint4(hw[0], hw[1], hw[2], hw[3]);
  *(uint4*)(pl + dst) = make_uint4(lw[0], lw[1], lw[2], lw[3]);
}

// ---------------- pre-split MFMA GEMM, BK=32, global_load_lds ----------------
// XCD-swizzled 1D grid. mode 1: QKV (768 blocks, N=3072, scatter). mode 0:
// out-proj (256 blocks, N=1024, store).
__global__ __launch_bounds__(256, 3) void gemm32(
    const ushort* __restrict__ aph, const ushort* __restrict__ apl,
    const ushort* __restrict__ bph, const ushort* __restrict__ bpl,
    const float* __restrict__ bias, float* __restrict__ Cout,
    float* __restrict__ Qb, float* __restrict__ Kb, float* __restrict__ Vb,
    int N, int mode) {
  __shared__ __align__(16) ushort Ah[128 * 32], Al[128 * 32];
  __shared__ __align__(16) ushort Bh[128 * 32], Bl[128 * 32];
  const int t = threadIdx.x, lane = t & 63, w = t >> 6;
  const int wm = w >> 1, wn = w & 1, fr = lane & 15, fg = lane >> 4;

  // XCD-aware decode: each XCD owns a 2D sub-tile of the (m,n) block grid
  const int bid = blockIdx.x;
  const int xcd = bid & 7, slot = bid >> 3;
  int n0, m0;
  if (mode == 1) {          // 24 n-chunks x 32 m-chunks; XCD = 12n x 8m
    int ns = slot % 12, ms = slot / 12;
    n0 = ((xcd & 1) * 12 + ns) << 7;
    m0 = ((xcd >> 1) * 8 + ms) << 7;
  } else {                  // 8 n-chunks x 32 m-chunks; XCD = 8n x 4m
    n0 = (slot & 7) << 7;
    m0 = (xcd * 4 + (slot >> 3)) << 7;
  }

  f32x4 acc[4][4];
#pragma unroll
  for (int i = 0; i < 4; i++)
#pragma unroll
    for (int j = 0; j < 4; j++) acc[i][j] = (f32x4){0.f, 0.f, 0.f, 0.f};

  // wave w stages one plane: 128 rows x 32 ushorts = 8KB = 8 x gll16
  const ushort* pl4 = (w == 0) ? aph : (w == 1) ? apl : (w == 2) ? bph : bpl;
  ushort* ld4 = (w == 0) ? Ah : (w == 1) ? Al : (w == 2) ? Bh : Bl;
  const int rb = (w < 2) ? m0 : n0;

  for (int kt = 0; kt < 1024; kt += 32) {
    __syncthreads();   // previous tile consumed
#pragma unroll
    for (int i = 0; i < 8; i++) {
      const ushort* src = pl4 + (size_t)(rb + i * 16 + (lane >> 2)) * 1024 +
                          kt + ((lane & 3) << 3);
      gll16(src, &ld4[i * 512]);
    }
    __syncthreads();   // vmcnt drained by compiler

    bfrag ah[4], al[4];
#pragma unroll
    for (int i = 0; i < 4; i++) {
      int r = wm * 64 + i * 16 + fr;
      int ad = r * 32 + ((fg ^ (r & 3) ^ ((r >> 2) & 3)) << 3);
      ah[i] = *(const bfrag*)&Ah[ad];
      al[i] = *(const bfrag*)&Al[ad];
    }
#pragma unroll
    for (int j = 0; j < 4; j++) {
      int r = wn * 64 + j * 16 + fr;
      int ad = r * 32 + ((fg ^ (r & 3) ^ ((r >> 2) & 3)) << 3);
      bfrag bh = *(const bfrag*)&Bh[ad];
      bfrag bl = *(const bfrag*)&Bl[ad];
#pragma unroll
      for (int i = 0; i < 4; i++) {
        acc[i][j] = __builtin_amdgcn_mfma_f32_16x16x32_bf16(ah[i], bh, acc[i][j], 0, 0, 0);
        acc[i][j] = __builtin_amdgcn_mfma_f32_16x16x32_bf16(ah[i], bl, acc[i][j], 0, 0, 0);
        acc[i][j] = __builtin_amdgcn_mfma_f32_16x16x32_bf16(al[i], bh, acc[i][j], 0, 0, 0);
      }
    }
  }

  // epilogue: C/D col = fr, row = fg*4 + reg
#pragma unroll
  for (int j = 0; j < 4; j++) {
    const int n = n0 + wn * 64 + j * 16 + fr;
    const float bb = bias[n];
#pragma unroll
    for (int i = 0; i < 4; i++) {
#pragma unroll
      for (int reg = 0; reg < 4; reg++) {
        const int m = m0 + wm * 64 + i * 16 + fg * 4 + reg;
        const float val = acc[i][j][reg] + bb;
        if (mode == 0) {
          Cout[(size_t)m * N + n] = val;
        } else {
          const int which = n >> 10;
          const int h = (n >> 6) & (HEADS - 1);
          const int d = n & (HDIM - 1);
          const int b = m >> 11, s = m & (SEQ - 1);
          float* base = (which == 0) ? Qb : ((which == 1) ? Kb : Vb);
          base[(((size_t)(b * HEADS + h)) * SEQ + s) * HDIM + d] = val;
        }
      }
    }
  }
}

// ---- RoPE + split: Q planes linear (scaled 1/8), K planes swizzled ----
__global__ __launch_bounds__(256) void rope_split_k(
    const float* __restrict__ Qb, const float* __restrict__ Kb,
    const float* __restrict__ ctab, const float* __restrict__ stab,
    ushort* __restrict__ Qh, ushort* __restrict__ Ql,
    ushort* __restrict__ Kh, ushort* __restrict__ Kl) {
  int idx = blockIdx.x * 256 + threadIdx.x;   // row*4 + dq
  int row = idx >> 2, dq = idx & 3;
  int d0 = dq * 8;
  int s = row & (SEQ - 1);
  const bool isQ = (blockIdx.y == 0);
  const float* P = (isQ ? Qb : Kb) + (size_t)row * 64;
  float4 a0 = *(const float4*)(P + d0), a1 = *(const float4*)(P + d0 + 4);
  float4 b0 = *(const float4*)(P + d0 + 32), b1 = *(const float4*)(P + d0 + 36);
  float4 c0 = *(const float4*)(ctab + s * 32 + d0), c1 = *(const float4*)(ctab + s * 32 + d0 + 4);
  float4 s0 = *(const float4*)(stab + s * 32 + d0), s1 = *(const float4*)(stab + s * 32 + d0 + 4);
  float lo[8] = {a0.x, a0.y, a0.z, a0.w, a1.x, a1.y, a1.z, a1.w};
  float hi[8] = {b0.x, b0.y, b0.z, b0.w, b1.x, b1.y, b1.z, b1.w};
  float cc[8] = {c0.x, c0.y, c0.z, c0.w, c1.x, c1.y, c1.z, c1.w};
  float ss[8] = {s0.x, s0.y, s0.z, s0.w, s1.x, s1.y, s1.z, s1.w};
  const float sc = isQ ? 0.125f : 1.0f;
  unsigned lh[4], ll[4], hh[4], hl[4];
#pragma unroll
  for (int i = 0; i < 4; i++) {
    float n0a = (lo[2 * i] * cc[2 * i] - hi[2 * i] * ss[2 * i]) * sc;
    float n0b = (lo[2 * i + 1] * cc[2 * i + 1] - hi[2 * i + 1] * ss[2 * i + 1]) * sc;
    float n1a = (hi[2 * i] * cc[2 * i] + lo[2 * i] * ss[2 * i]) * sc;
    float n1b = (hi[2 * i + 1] * cc[2 * i + 1] + lo[2 * i + 1] * ss[2 * i + 1]) * sc;
    unsigned short x0, y0, x1, y1;
    split2(n0a, x0, y0); split2(n0b, x1, y1);
    lh[i] = (unsigned)x0 | ((unsigned)x1 << 16);
    ll[i] = (unsigned)y0 | ((unsigned)y1 << 16);
    split2(n1a, x0, y0); split2(n1b, x1, y1);
    hh[i] = (unsigned)x0 | ((unsigned)x1 << 16);
    hl[i] = (unsigned)y0 | ((unsigned)y1 << 16);
  }
  size_t base = (size_t)row * 64;
  if (isQ) {
    *(uint4*)(Qh + base + d0) = make_uint4(lh[0], lh[1], lh[2], lh[3]);
    *(uint4*)(Ql + base + d0) = make_uint4(ll[0], ll[1], ll[2], ll[3]);
    *(uint4*)(Qh + base + d0 + 32) = make_uint4(hh[0], hh[1], hh[2], hh[3]);
    *(uint4*)(Ql + base + d0 + 32) = make_uint4(hl[0], hl[1], hl[2], hl[3]);
  } else {
    int glo = (dq ^ (s & 7)) << 3;
    int ghi = ((dq + 4) ^ (s & 7)) << 3;
    *(uint4*)(Kh + base + glo) = make_uint4(lh[0], lh[1], lh[2], lh[3]);
    *(uint4*)(Kl + base + glo) = make_uint4(ll[0], ll[1], ll[2], ll[3]);
    *(uint4*)(Kh + base + ghi) = make_uint4(hh[0], hh[1], hh[2], hh[3]);
    *(uint4*)(Kl + base + ghi) = make_uint4(hl[0], hl[1], hl[2], hl[3]);
  }
}

// ---- V transpose+split: Vb[bh][s][d] -> Vt planes [(bh*64+d)][s swizzled] ----
__global__ __launch_bounds__(256) void vtrans_split(const float* __restrict__ Vb,
                                                    ushort* __restrict__ Vth,
                                                    ushort* __restrict__ Vtl) {
  __shared__ float ftile[64][65];
  const int t = threadIdx.x;
  const int kt = blockIdx.x, bh = blockIdx.y;   // kt: 64-key tile
  {
    int s_loc = t >> 2, dc = (t & 3) * 16;
    const float* p = Vb + ((size_t)(bh * SEQ) + kt * 64 + s_loc) * 64 + dc;
#pragma unroll
    for (int j = 0; j < 4; j++) {
      float4 v = *(const float4*)(p + j * 4);
      ftile[s_loc][dc + j * 4 + 0] = v.x;
      ftile[s_loc][dc + j * 4 + 1] = v.y;
      ftile[s_loc][dc + j * 4 + 2] = v.z;
      ftile[s_loc][dc + j * 4 + 3] = v.w;
    }
  }
  __syncthreads();
  int d = t >> 2, sc = (t & 3) * 16;
  size_t rowb = ((size_t)(bh * 64 + d)) * SEQ + kt * 64;
#pragma unroll
  for (int jg = 0; jg < 2; jg++) {
    unsigned hw[4], lw[4];
#pragma unroll
    for (int i = 0; i < 4; i++) {
      unsigned short h0, l0, h1, l1;
      split2(ftile[sc + jg * 8 + 2 * i][d], h0, l0);
      split2(ftile[sc + jg * 8 + 2 * i + 1][d], h1, l1);
      hw[i] = (unsigned)h0 | ((unsigned)h1 << 16);
      lw[i] = (unsigned)l0 | ((unsigned)l1 << 16);
    }
    int gsrc = ((sc >> 3) + jg) & 7;
    int swz = (gsrc ^ (d & 7) ^ ((d >> 3) & 7)) << 3;
    *(uint4*)(Vth + rowb + swz) = make_uint4(hw[0], hw[1], hw[2], hw[3]);
    *(uint4*)(Vtl + rowb + swz) = make_uint4(lw[0], lw[1], lw[2], lw[3]);
  }
}

// ---------------- MFMA flash attention, bf16x3, pre-split inputs ----------------
// XCD-swizzled 1D grid (512): each XCD owns 4 bh's -> K/V planes L2-resident.
// Double-buffered K/V LDS (64KB, still 2 blocks/CU): STAGE(next) || COMPUTE(cur),
// one barrier per K-tile -> load latency hides under compute.
__global__ __launch_bounds__(256, 2) void attn_mfma2(
    const ushort* __restrict__ Qh, const ushort* __restrict__ Ql,
    const ushort* __restrict__ Kh, const ushort* __restrict__ Kl,
    const ushort* __restrict__ Vth, const ushort* __restrict__ Vtl,
    float* __restrict__ Ab) {
  __shared__ __align__(16) ushort KsH0[64 * 64], KsL0[64 * 64];
  __shared__ __align__(16) ushort VsH0[64 * 64], VsL0[64 * 64];
  __shared__ __align__(16) ushort KsH1[64 * 64], KsL1[64 * 64];
  __shared__ __align__(16) ushort VsH1[64 * 64], VsL1[64 * 64];

  const int t = threadIdx.x, lane = t & 63, w = t >> 6;
  const int fr = lane & 15, fg = lane >> 4;

  // XCD-aware decode: xcd owns bh in {4*xcd .. 4*xcd+3}, 16 q-blocks each
  const int bid = blockIdx.x;
  const int xcd = bid & 7, slot = bid >> 3;
  const int bh = xcd * 4 + (slot >> 4);
  const int q0 = (slot & 15) * 128;
  const int b = bh >> 4, h = bh & (HEADS - 1);

  // Q fragments from pre-split planes (linear)
  bfrag qh[2][2], ql[2][2];
#pragma unroll
  for (int qf = 0; qf < 2; qf++)
#pragma unroll
    for (int kk = 0; kk < 2; kk++) {
      size_t off = ((size_t)bh * SEQ + q0 + w * 32 + qf * 16 + fr) * 64 + kk * 32 + fg * 8;
      U4B uh, ul;
      uh.u = *(const uint4*)(Qh + off);
      ul.u = *(const uint4*)(Ql + off);
      qh[qf][kk] = uh.b;
      ql[qf][kk] = ul.b;
    }

  f32x4 Oacc[2][4];
#pragma unroll
  for (int qf = 0; qf < 2; qf++)
#pragma unroll
    for (int df = 0; df < 4; df++) Oacc[qf][df] = (f32x4){0.f, 0.f, 0.f, 0.f};
  float m_i[2] = {-1e30f, -1e30f}, l_i[2] = {0.f, 0.f};

  const int srcA = fr + ((fg & 1) << 5);   // (fallback path only)
  const int kisel = fg >> 1;

  // ---- STAGE: wave w loads one plane of the K-tile into given buffers ----
  auto STAGE = [&](ushort* KH, ushort* KL, ushort* VH, ushort* VL, int kt) {
    if (w < 2) {
      const ushort* p = w ? Kl : Kh;
      ushort* ld = w ? KL : KH;
#pragma unroll
      for (int i = 0; i < 8; i++) {
        const ushort* src = p + ((size_t)bh * SEQ + kt + i * 8 + (lane >> 3)) * 64 + ((lane & 7) << 3);
        gll16(src, &ld[i * 512]);
      }
    } else {
      const ushort* p = (w == 3) ? Vtl : Vth;
      ushort* ld = (w == 3) ? VL : VH;
#pragma unroll
      for (int i = 0; i < 8; i++) {
        const ushort* src = p + ((size_t)(bh * 64) + i * 8 + (lane >> 3)) * SEQ + kt + ((lane & 7) << 3);
        gll16(src, &ld[i * 512]);
      }
    }
  };

  // ---- COMPUTE: one 64-key tile from given buffers ----
  auto COMPUTE = [&](const ushort* KsH, const ushort* KsL,
                     const ushort* VsH, const ushort* VsL) {
    // QK^T swapped: sacc[ki][qf]: key = 16ki + 4fg + r, q = 16qf + fr
    f32x4 sacc[4][2];
#pragma unroll
    for (int ki = 0; ki < 4; ki++)
#pragma unroll
      for (int qf = 0; qf < 2; qf++) sacc[ki][qf] = (f32x4){0.f, 0.f, 0.f, 0.f};
#pragma unroll
    for (int kk = 0; kk < 2; kk++) {
#pragma unroll
      for (int ki = 0; ki < 4; ki++) {
        int r = ki * 16 + fr;
        int ad = r * 64 + (((kk * 4 + fg) ^ (r & 7)) << 3);
        bfrag kh = *(const bfrag*)&KsH[ad];
        bfrag kl = *(const bfrag*)&KsL[ad];
#pragma unroll
        for (int qf = 0; qf < 2; qf++) {
          sacc[ki][qf] = __builtin_amdgcn_mfma_f32_16x16x32_bf16(kh, qh[qf][kk], sacc[ki][qf], 0, 0, 0);
          sacc[ki][qf] = __builtin_amdgcn_mfma_f32_16x16x32_bf16(kh, ql[qf][kk], sacc[ki][qf], 0, 0, 0);
          sacc[ki][qf] = __builtin_amdgcn_mfma_f32_16x16x32_bf16(kl, qh[qf][kk], sacc[ki][qf], 0, 0, 0);
        }
      }
    }

#ifdef MFMA16
    bhalf4 paH[2][4], paL[2][4];   // [qf][ki] x16 A-frags (lane-local P)
#else
    unsigned phv[2][2][4], plv[2][2][4];   // [qf][pair][ki]
#endif
    // online softmax; lane's q = qf*16 + fr
#pragma unroll
    for (int qf = 0; qf < 2; qf++) {
      float mm = -1e30f;
#pragma unroll
      for (int ki = 0; ki < 4; ki++)
#pragma unroll
        for (int r = 0; r < 4; r++) mm = fmaxf(mm, sacc[ki][qf][r]);
      mm = fmaxf(mm, __shfl_xor(mm, 16));
      mm = fmaxf(mm, __shfl_xor(mm, 32));
      float mn = fmaxf(m_i[qf], mm);
      float alpha = __expf(m_i[qf] - mn);
      m_i[qf] = mn;
      float rs = 0.f;
      float pv[4][4];
#pragma unroll
      for (int ki = 0; ki < 4; ki++)
#pragma unroll
        for (int r = 0; r < 4; r++) {
          float p = __expf(sacc[ki][qf][r] - mn);
          pv[ki][r] = p;
          rs += p;
        }
      rs += __shfl_xor(rs, 16);
      rs += __shfl_xor(rs, 32);
      l_i[qf] = l_i[qf] * alpha + rs;
#ifdef MFMA16
#pragma unroll
      for (int ki = 0; ki < 4; ki++) {
        unsigned h0 = cvt_pk_bf16(pv[ki][0], pv[ki][1]);
        unsigned h1 = cvt_pk_bf16(pv[ki][2], pv[ki][3]);
        float e00 = __uint_as_float(h0 << 16), e01 = __uint_as_float(h0 & 0xFFFF0000u);
        float e10 = __uint_as_float(h1 << 16), e11 = __uint_as_float(h1 & 0xFFFF0000u);
        unsigned l0 = cvt_pk_bf16(pv[ki][0] - e00, pv[ki][1] - e01);
        unsigned l1 = cvt_pk_bf16(pv[ki][2] - e10, pv[ki][3] - e11);
        U2B th, tl;
        th.u = make_uint2(h0, h1);
        tl.u = make_uint2(l0, l1);
        paH[qf][ki] = th.b;
        paL[qf][ki] = tl.b;
      }
#else
#pragma unroll
      for (int ki = 0; ki < 4; ki++)
#pragma unroll
        for (int pr = 0; pr < 2; pr++) {
          float p0 = pv[ki][2 * pr], p1 = pv[ki][2 * pr + 1];
          unsigned hp = cvt_pk_bf16(p0, p1);
          float h0 = __uint_as_float(hp << 16);
          float h1 = __uint_as_float(hp & 0xFFFF0000u);
          phv[qf][pr][ki] = hp;
          plv[qf][pr][ki] = cvt_pk_bf16(p0 - h0, p1 - h1);
        }
#endif
      // rescale Oacc rows (their q = 16qf + 4fg + reg)
      float ar[4];
#pragma unroll
      for (int r = 0; r < 4; r++) ar[r] = __shfl(alpha, 4 * fg + r);
#pragma unroll
      for (int df = 0; df < 4; df++)
#pragma unroll
        for (int r = 0; r < 4; r++) Oacc[qf][df][r] *= ar[r];
    }

#ifdef MFMA16
    // PV via 16x16x16: A = own packed P (lane-local); B = Vt b64 reads
#pragma unroll
    for (int ki = 0; ki < 4; ki++) {
      bhalf4 vh[4], vl[4];
#pragma unroll
      for (int df = 0; df < 4; df++) {
        int d = df * 16 + fr;
        int ad = d * 64 + ((((2 * ki + (fg >> 1)) ^ (d & 7) ^ ((d >> 3) & 7))) << 3) + ((fg & 1) << 2);
        vh[df] = *(const bhalf4*)&VsH[ad];
        vl[df] = *(const bhalf4*)&VsL[ad];
      }
#pragma unroll
      for (int qf = 0; qf < 2; qf++)
#pragma unroll
        for (int df = 0; df < 4; df++) {
          Oacc[qf][df] = MFMA16(paH[qf][ki], vh[df], Oacc[qf][df]);
          Oacc[qf][df] = MFMA16(paH[qf][ki], vl[df], Oacc[qf][df]);
          Oacc[qf][df] = MFMA16(paL[qf][ki], vh[df], Oacc[qf][df]);
        }
    }
#else
    // Fallback PV via 16x16x32 + shfl regather of P fragments
#pragma unroll
    for (int kk = 0; kk < 2; kk++) {
      bfrag vh[4], vl[4];
#pragma unroll
      for (int df = 0; df < 4; df++) {
        int d = df * 16 + fr;
        int ad = d * 64 + (((kk * 4 + fg) ^ (d & 7) ^ ((d >> 3) & 7)) << 3);
        vh[df] = *(const bfrag*)&VsH[ad];
        vl[df] = *(const bfrag*)&VsL[ad];
      }
#pragma unroll
      for (int qf = 0; qf < 2; qf++) {
        U4B pah, pal;
#pragma unroll
        for (int wd = 0; wd < 4; wd++) {
          int src = srcA + ((wd >> 1) << 4);
          int pr = wd & 1;
          unsigned a0 = (unsigned)__shfl((int)phv[qf][pr][2 * kk], src);
          unsigned a1 = (unsigned)__shfl((int)phv[qf][pr][2 * kk + 1], src);
          unsigned b0 = (unsigned)__shfl((int)plv[qf][pr][2 * kk], src);
          unsigned b1 = (unsigned)__shfl((int)plv[qf][pr][2 * kk + 1], src);
          (&pah.u.x)[wd] = kisel ? a1 : a0;
          (&pal.u.x)[wd] = kisel ? b1 : b0;
        }
#pragma unroll
        for (int df = 0; df < 4; df++) {
          Oacc[qf][df] = __builtin_amdgcn_mfma_f32_16x16x32_bf16(pah.b, vh[df], Oacc[qf][df], 0, 0, 0);
          Oacc[qf][df] = __builtin_amdgcn_mfma_f32_16x16x32_bf16(pah.b, vl[df], Oacc[qf][df], 0, 0, 0);
          Oacc[qf][df] = __builtin_amdgcn_mfma_f32_16x16x32_bf16(pal.b, vh[df], Oacc[qf][df], 0, 0, 0);
        }
      }
    }
#endif
  };

  // ---- 2-phase double-buffered main loop (static buffer names) ----
  STAGE(KsH0, KsL0, VsH0, VsL0, 0);
  __syncthreads();
  for (int kt = 0; kt < SEQ; kt += 128) {
    STAGE(KsH1, KsL1, VsH1, VsL1, kt + 64);
    COMPUTE(KsH0, KsL0, VsH0, VsL0);
    __syncthreads();
    if (kt + 128 < SEQ) STAGE(KsH0, KsL0, VsH0, VsL0, kt + 128);
    COMPUTE(KsH1, KsL1, VsH1, VsL1);
    __syncthreads();
  }

  // epilogue: Ab[m][1024], m = b*SEQ+s, col = h*64+d
#pragma unroll
  for (int qf = 0; qf < 2; qf++) {
    float lr[4];
#pragma unroll
    for (int r = 0; r < 4; r++) lr[r] = 1.0f / __shfl(l_i[qf], 4 * fg + r);
#pragma unroll
    for (int df = 0; df < 4; df++)
#pragma unroll
      for (int r = 0; r < 4; r++) {
        int s = q0 + w * 32 + qf * 16 + 4 * fg + r;
        int d = df * 16 + fr;
        Ab[((size_t)(b * SEQ + s)) * 1024 + h * 64 + d] = Oacc[qf][df][r] * lr[r];
      }
  }
}

extern "C" void kernel_launch(void* const* d_in, const int* in_sizes, int n_in,
                              void* d_out, int out_size, void* d_ws, size_t ws_size,
                              hipStream_t stream) {
  const float* x    = (const float*)d_in[0];
  const float* Wqkv = (const float*)d_in[1];
  const float* bqkv = (const float*)d_in[2];
  const float* Wout = (const float*)d_in[3];
  const float* bout = (const float*)d_in[4];
  float* out = (float*)d_out;

  char* W = (char*)d_ws;
  float* ctab = (float*)W;  W += (size_t)SEQ * 32 * 4;
  float* stab = (float*)W;  W += (size_t)SEQ * 32 * 4;
  float* Qb   = (float*)W;  W += (size_t)16 << 20;   // alias: Abf after rope
  float* Kb   = (float*)W;  W += (size_t)16 << 20;   // alias: abh+abl after rope
  float* Vb   = (float*)W;  W += (size_t)16 << 20;
  ushort* xh  = (ushort*)W; W += (size_t)8 << 20;    // alias: Qhp after gemm1
  ushort* xl  = (ushort*)W; W += (size_t)8 << 20;    // alias: Qlp after gemm1
  ushort* wqh = (ushort*)W; W += (size_t)6 << 20;
  ushort* wql = (ushort*)W; W += (size_t)6 << 20;
  ushort* woh = (ushort*)W; W += (size_t)2 << 20;
  ushort* wol = (ushort*)W; W += (size_t)2 << 20;
  ushort* Khp = (ushort*)W; W += (size_t)8 << 20;
  ushort* Klp = (ushort*)W; W += (size_t)8 << 20;
  ushort* Vthp = (ushort*)W; W += (size_t)8 << 20;
  ushort* Vtlp = (ushort*)W; W += (size_t)8 << 20;
  ushort* Qhp = xh;                   // xh/xl dead after gemm1
  ushort* Qlp = xl;
  float* Abf = Qb;                    // Qb fp32 dead after rope_split
  ushort* abh = (ushort*)Kb;          // Kb fp32 dead after rope_split
  ushort* abl = abh + ((size_t)4 << 20);

  hipLaunchKernelGGL(rope_table_k, dim3(SEQ * 32 / 256), dim3(256), 0, stream, ctab, stab);
  hipLaunchKernelGGL(split_swz4, dim3(4096 / 2), dim3(256), 0, stream, x, xh, xl);
  hipLaunchKernelGGL(split_swz4, dim3(3072 / 2), dim3(256), 0, stream, Wqkv, wqh, wql);
  hipLaunchKernelGGL(split_swz4, dim3(1024 / 2), dim3(256), 0, stream, Wout, woh, wol);
  hipLaunchKernelGGL(gemm32, dim3(768), dim3(256), 0, stream,
                     xh, xl, wqh, wql, bqkv, (float*)nullptr, Qb, Kb, Vb, 3072, 1);
  hipLaunchKernelGGL(rope_split_k, dim3(BATCH * HEADS * SEQ * 4 / 256, 2), dim3(256), 0, stream,
                     Qb, Kb, ctab, stab, Qhp, Qlp, Khp, Klp);
  hipLaunchKernelGGL(vtrans_split, dim3(SEQ / 64, BATCH * HEADS), dim3(256), 0, stream,
                     Vb, Vthp, Vtlp);
  hipLaunchKernelGGL(attn_mfma2, dim3(512), dim3(256), 0, stream,
                     Qhp, Qlp, Khp, Klp, Vthp, Vtlp, Abf);
  hipLaunchKernelGGL(split_swz4, dim3(4096 / 2), dim3(256), 0, stream, Abf, abh, abl);
  hipLaunchKernelGGL(gemm32, dim3(256), dim3(256), 0, stream,
                     abh, abl, woh, wol, bout, out,
                     (float*)nullptr, (float*)nullptr, (float*)nullptr, 1024, 0);
}

// Round 7
// 358.207 us; speedup vs baseline: 1.8132x; 1.0461x over previous
//
#include <hip/hip_runtime.h>
#include <hip/hip_bf16.h>
#include <cstdint>

#define HIDDEN 1024
#define HEADS 16
#define HDIM 64
#define BATCH 2
#define SEQ 2048

typedef __attribute__((ext_vector_type(8))) short bfrag;   // 8 bf16 (4 VGPRs)
typedef __attribute__((ext_vector_type(4))) short bhalf4;  // 4 bf16 (2 VGPRs)
typedef __attribute__((ext_vector_type(4))) float f32x4;   // MFMA C/D

union U4B { uint4 u; bfrag b; };
union U2B { uint2 u; bhalf4 b; };

#if defined(__has_builtin)
#if __has_builtin(__builtin_amdgcn_mfma_f32_16x16x16bf16_1k)
#define MFMA16(a, b, c) __builtin_amdgcn_mfma_f32_16x16x16bf16_1k(a, b, c, 0, 0, 0)
#elif __has_builtin(__builtin_amdgcn_mfma_f32_16x16x16_bf16)
#define MFMA16(a, b, c) __builtin_amdgcn_mfma_f32_16x16x16_bf16(a, b, c, 0, 0, 0)
#endif
#endif

// round-to-nearest-even f32 -> bf16 bits
__device__ inline unsigned short f2bf(float f) {
  unsigned u = __float_as_uint(f);
  return (unsigned short)((u + 0x7FFFu + ((u >> 16) & 1u)) >> 16);
}
// Ootomo split: f ~= hi + lo
__device__ inline void split2(float f, unsigned short& h, unsigned short& l) {
  unsigned u = __float_as_uint(f);
  unsigned hb = (u + 0x7FFFu + ((u >> 16) & 1u)) & 0xFFFF0000u;
  h = (unsigned short)(hb >> 16);
  l = f2bf(f - __uint_as_float(hb));
}
__device__ inline unsigned cvt_pk_bf16(float a, float b) {
  unsigned d;
  asm("v_cvt_pk_bf16_f32 %0, %1, %2" : "=v"(d) : "v"(a), "v"(b));
  return d;
}
// async global->LDS 16B per lane; LDS dst wave-uniform base + lane*16
__device__ inline void gll16(const void* g, void* l) {
  __builtin_amdgcn_global_load_lds(
      (const __attribute__((address_space(1))) void*)g,
      (__attribute__((address_space(3))) void*)l, 16, 0, 0);
}

// ---------------- RoPE cos/sin tables: [S][32] each ----------------
__global__ __launch_bounds__(256) void rope_table_k(float* __restrict__ ctab,
                                                    float* __restrict__ stab) {
  int idx = blockIdx.x * 256 + threadIdx.x;
  int s = idx >> 5, i = idx & 31;
  float inv = powf(10000.0f, -(float)i / 32.0f);
  float a = (float)s * inv;
  ctab[idx] = cosf(a);
  stab[idx] = sinf(a);
}

// ---- split fp32 [R][1024] -> bf16 hi/lo planes, pre-swizzled for BK=32 ----
__global__ __launch_bounds__(256) void split_swz4(const float* __restrict__ in,
                                                  ushort* __restrict__ ph,
                                                  ushort* __restrict__ pl) {
  int gid = blockIdx.x * 256 + threadIdx.x;   // one 8-elem granule each
  int r = gid >> 7, g = gid & 127;
  const float* p = in + (size_t)r * 1024 + g * 8;
  float4 a = *(const float4*)p, b = *(const float4*)(p + 4);
  float v[8] = {a.x, a.y, a.z, a.w, b.x, b.y, b.z, b.w};
  unsigned hw[4], lw[4];
#pragma unroll
  for (int i = 0; i < 4; i++) {
    unsigned short h0, l0, h1, l1;
    split2(v[2 * i], h0, l0);
    split2(v[2 * i + 1], h1, l1);
    hw[i] = (unsigned)h0 | ((unsigned)h1 << 16);
    lw[i] = (unsigned)l0 | ((unsigned)l1 << 16);
  }
  size_t dst = (size_t)r * 1024 + (g >> 2) * 32 +
               ((((g & 3) ^ (r & 3) ^ ((r >> 2) & 3))) << 3);
  *(uint4*)(ph + dst) = make_uint4(hw[0], hw[1], hw[2], hw[3]);
  *(uint4*)(pl + dst) = make_uint4(lw[0], lw[1], lw[2], lw[3]);
}

// ---------------- pre-split MFMA GEMM, BK=32, global_load_lds ----------------
// XCD-swizzled 1D grid; double-buffered staging: STAGE(next) || COMPUTE(cur),
// one barrier per K-tile -> load latency hides under MFMA.
// mode 1: QKV (768 blocks, N=3072, scatter). mode 0: out-proj (256, N=1024).
__global__ __launch_bounds__(256, 2) void gemm32(
    const ushort* __restrict__ aph, const ushort* __restrict__ apl,
    const ushort* __restrict__ bph, const ushort* __restrict__ bpl,
    const float* __restrict__ bias, float* __restrict__ Cout,
    float* __restrict__ Qb, float* __restrict__ Kb, float* __restrict__ Vb,
    int N, int mode) {
  __shared__ __align__(16) ushort Ah0[128 * 32], Al0[128 * 32];
  __shared__ __align__(16) ushort Bh0[128 * 32], Bl0[128 * 32];
  __shared__ __align__(16) ushort Ah1[128 * 32], Al1[128 * 32];
  __shared__ __align__(16) ushort Bh1[128 * 32], Bl1[128 * 32];
  const int t = threadIdx.x, lane = t & 63, w = t >> 6;
  const int wm = w >> 1, wn = w & 1, fr = lane & 15, fg = lane >> 4;

  // XCD-aware decode: each XCD owns a 2D sub-tile of the (m,n) block grid
  const int bid = blockIdx.x;
  const int xcd = bid & 7, slot = bid >> 3;
  int n0, m0;
  if (mode == 1) {          // 24 n-chunks x 32 m-chunks; XCD = 12n x 8m
    int ns = slot % 12, ms = slot / 12;
    n0 = ((xcd & 1) * 12 + ns) << 7;
    m0 = ((xcd >> 1) * 8 + ms) << 7;
  } else {                  // 8 n-chunks x 32 m-chunks; XCD = 8n x 4m
    n0 = (slot & 7) << 7;
    m0 = (xcd * 4 + (slot >> 3)) << 7;
  }

  f32x4 acc[4][4];
#pragma unroll
  for (int i = 0; i < 4; i++)
#pragma unroll
    for (int j = 0; j < 4; j++) acc[i][j] = (f32x4){0.f, 0.f, 0.f, 0.f};

  // wave w owns one plane (A-hi / A-lo / B-hi / B-lo), one dbuf copy each
  const ushort* pl4 = (w == 0) ? aph : (w == 1) ? apl : (w == 2) ? bph : bpl;
  ushort* ld0 = (w == 0) ? Ah0 : (w == 1) ? Al0 : (w == 2) ? Bh0 : Bl0;
  ushort* ld1 = (w == 0) ? Ah1 : (w == 1) ? Al1 : (w == 2) ? Bh1 : Bl1;
  const int rb = (w < 2) ? m0 : n0;

  auto STAGE = [&](ushort* ld, int kt) {
#pragma unroll
    for (int i = 0; i < 8; i++) {
      const ushort* src = pl4 + (size_t)(rb + i * 16 + (lane >> 2)) * 1024 +
                          kt + ((lane & 3) << 3);
      gll16(src, &ld[i * 512]);
    }
  };

  auto COMPUTE = [&](const ushort* Ah, const ushort* Al,
                     const ushort* Bh, const ushort* Bl) {
    bfrag ah[4], al[4];
#pragma unroll
    for (int i = 0; i < 4; i++) {
      int r = wm * 64 + i * 16 + fr;
      int ad = r * 32 + ((fg ^ (r & 3) ^ ((r >> 2) & 3)) << 3);
      ah[i] = *(const bfrag*)&Ah[ad];
      al[i] = *(const bfrag*)&Al[ad];
    }
#pragma unroll
    for (int j = 0; j < 4; j++) {
      int r = wn * 64 + j * 16 + fr;
      int ad = r * 32 + ((fg ^ (r & 3) ^ ((r >> 2) & 3)) << 3);
      bfrag bh = *(const bfrag*)&Bh[ad];
      bfrag bl = *(const bfrag*)&Bl[ad];
#pragma unroll
      for (int i = 0; i < 4; i++) {
        acc[i][j] = __builtin_amdgcn_mfma_f32_16x16x32_bf16(ah[i], bh, acc[i][j], 0, 0, 0);
        acc[i][j] = __builtin_amdgcn_mfma_f32_16x16x32_bf16(ah[i], bl, acc[i][j], 0, 0, 0);
        acc[i][j] = __builtin_amdgcn_mfma_f32_16x16x32_bf16(al[i], bh, acc[i][j], 0, 0, 0);
      }
    }
  };

  // 2-phase double-buffered K-loop (static buffer names)
  STAGE(ld0, 0);
  __syncthreads();
  for (int kt = 0; kt < 1024; kt += 64) {
    STAGE(ld1, kt + 32);
    COMPUTE(Ah0, Al0, Bh0, Bl0);
    __syncthreads();
    if (kt + 64 < 1024) STAGE(ld0, kt + 64);
    COMPUTE(Ah1, Al1, Bh1, Bl1);
    __syncthreads();
  }

  // epilogue: C/D col = fr, row = fg*4 + reg
#pragma unroll
  for (int j = 0; j < 4; j++) {
    const int n = n0 + wn * 64 + j * 16 + fr;
    const float bb = bias[n];
#pragma unroll
    for (int i = 0; i < 4; i++) {
#pragma unroll
      for (int reg = 0; reg < 4; reg++) {
        const int m = m0 + wm * 64 + i * 16 + fg * 4 + reg;
        const float val = acc[i][j][reg] + bb;
        if (mode == 0) {
          Cout[(size_t)m * N + n] = val;
        } else {
          const int which = n >> 10;
          const int h = (n >> 6) & (HEADS - 1);
          const int d = n & (HDIM - 1);
          const int b = m >> 11, s = m & (SEQ - 1);
          float* base = (which == 0) ? Qb : ((which == 1) ? Kb : Vb);
          base[(((size_t)(b * HEADS + h)) * SEQ + s) * HDIM + d] = val;
        }
      }
    }
  }
}

// ---- RoPE + split: Q planes linear (scaled 1/8), K planes swizzled ----
__global__ __launch_bounds__(256) void rope_split_k(
    const float* __restrict__ Qb, const float* __restrict__ Kb,
    const float* __restrict__ ctab, const float* __restrict__ stab,
    ushort* __restrict__ Qh, ushort* __restrict__ Ql,
    ushort* __restrict__ Kh, ushort* __restrict__ Kl) {
  int idx = blockIdx.x * 256 + threadIdx.x;   // row*4 + dq
  int row = idx >> 2, dq = idx & 3;
  int d0 = dq * 8;
  int s = row & (SEQ - 1);
  const bool isQ = (blockIdx.y == 0);
  const float* P = (isQ ? Qb : Kb) + (size_t)row * 64;
  float4 a0 = *(const float4*)(P + d0), a1 = *(const float4*)(P + d0 + 4);
  float4 b0 = *(const float4*)(P + d0 + 32), b1 = *(const float4*)(P + d0 + 36);
  float4 c0 = *(const float4*)(ctab + s * 32 + d0), c1 = *(const float4*)(ctab + s * 32 + d0 + 4);
  float4 s0 = *(const float4*)(stab + s * 32 + d0), s1 = *(const float4*)(stab + s * 32 + d0 + 4);
  float lo[8] = {a0.x, a0.y, a0.z, a0.w, a1.x, a1.y, a1.z, a1.w};
  float hi[8] = {b0.x, b0.y, b0.z, b0.w, b1.x, b1.y, b1.z, b1.w};
  float cc[8] = {c0.x, c0.y, c0.z, c0.w, c1.x, c1.y, c1.z, c1.w};
  float ss[8] = {s0.x, s0.y, s0.z, s0.w, s1.x, s1.y, s1.z, s1.w};
  const float sc = isQ ? 0.125f : 1.0f;
  unsigned lh[4], ll[4], hh[4], hl[4];
#pragma unroll
  for (int i = 0; i < 4; i++) {
    float n0a = (lo[2 * i] * cc[2 * i] - hi[2 * i] * ss[2 * i]) * sc;
    float n0b = (lo[2 * i + 1] * cc[2 * i + 1] - hi[2 * i + 1] * ss[2 * i + 1]) * sc;
    float n1a = (hi[2 * i] * cc[2 * i] + lo[2 * i] * ss[2 * i]) * sc;
    float n1b = (hi[2 * i + 1] * cc[2 * i + 1] + lo[2 * i + 1] * ss[2 * i + 1]) * sc;
    unsigned short x0, y0, x1, y1;
    split2(n0a, x0, y0); split2(n0b, x1, y1);
    lh[i] = (unsigned)x0 | ((unsigned)x1 << 16);
    ll[i] = (unsigned)y0 | ((unsigned)y1 << 16);
    split2(n1a, x0, y0); split2(n1b, x1, y1);
    hh[i] = (unsigned)x0 | ((unsigned)x1 << 16);
    hl[i] = (unsigned)y0 | ((unsigned)y1 << 16);
  }
  size_t base = (size_t)row * 64;
  if (isQ) {
    *(uint4*)(Qh + base + d0) = make_uint4(lh[0], lh[1], lh[2], lh[3]);
    *(uint4*)(Ql + base + d0) = make_uint4(ll[0], ll[1], ll[2], ll[3]);
    *(uint4*)(Qh + base + d0 + 32) = make_uint4(hh[0], hh[1], hh[2], hh[3]);
    *(uint4*)(Ql + base + d0 + 32) = make_uint4(hl[0], hl[1], hl[2], hl[3]);
  } else {
    int glo = (dq ^ (s & 7)) << 3;
    int ghi = ((dq + 4) ^ (s & 7)) << 3;
    *(uint4*)(Kh + base + glo) = make_uint4(lh[0], lh[1], lh[2], lh[3]);
    *(uint4*)(Kl + base + glo) = make_uint4(ll[0], ll[1], ll[2], ll[3]);
    *(uint4*)(Kh + base + ghi) = make_uint4(hh[0], hh[1], hh[2], hh[3]);
    *(uint4*)(Kl + base + ghi) = make_uint4(hl[0], hl[1], hl[2], hl[3]);
  }
}

// ---- V transpose+split: Vb[bh][s][d] -> Vt planes [(bh*64+d)][s swizzled] ----
__global__ __launch_bounds__(256) void vtrans_split(const float* __restrict__ Vb,
                                                    ushort* __restrict__ Vth,
                                                    ushort* __restrict__ Vtl) {
  __shared__ float ftile[64][65];
  const int t = threadIdx.x;
  const int kt = blockIdx.x, bh = blockIdx.y;   // kt: 64-key tile
  {
    int s_loc = t >> 2, dc = (t & 3) * 16;
    const float* p = Vb + ((size_t)(bh * SEQ) + kt * 64 + s_loc) * 64 + dc;
#pragma unroll
    for (int j = 0; j < 4; j++) {
      float4 v = *(const float4*)(p + j * 4);
      ftile[s_loc][dc + j * 4 + 0] = v.x;
      ftile[s_loc][dc + j * 4 + 1] = v.y;
      ftile[s_loc][dc + j * 4 + 2] = v.z;
      ftile[s_loc][dc + j * 4 + 3] = v.w;
    }
  }
  __syncthreads();
  int d = t >> 2, sc = (t & 3) * 16;
  size_t rowb = ((size_t)(bh * 64 + d)) * SEQ + kt * 64;
#pragma unroll
  for (int jg = 0; jg < 2; jg++) {
    unsigned hw[4], lw[4];
#pragma unroll
    for (int i = 0; i < 4; i++) {
      unsigned short h0, l0, h1, l1;
      split2(ftile[sc + jg * 8 + 2 * i][d], h0, l0);
      split2(ftile[sc + jg * 8 + 2 * i + 1][d], h1, l1);
      hw[i] = (unsigned)h0 | ((unsigned)h1 << 16);
      lw[i] = (unsigned)l0 | ((unsigned)l1 << 16);
    }
    int gsrc = ((sc >> 3) + jg) & 7;
    int swz = (gsrc ^ (d & 7) ^ ((d >> 3) & 7)) << 3;
    *(uint4*)(Vth + rowb + swz) = make_uint4(hw[0], hw[1], hw[2], hw[3]);
    *(uint4*)(Vtl + rowb + swz) = make_uint4(lw[0], lw[1], lw[2], lw[3]);
  }
}

// ---------------- MFMA flash attention, bf16x3, pre-split inputs ----------------
// XCD-swizzled 1D grid (512): each XCD owns 4 bh's -> K/V planes L2-resident.
// Double-buffered K/V LDS (64KB, 2 blocks/CU): STAGE(next) || COMPUTE(cur).
__global__ __launch_bounds__(256, 2) void attn_mfma2(
    const ushort* __restrict__ Qh, const ushort* __restrict__ Ql,
    const ushort* __restrict__ Kh, const ushort* __restrict__ Kl,
    const ushort* __restrict__ Vth, const ushort* __restrict__ Vtl,
    float* __restrict__ Ab) {
  __shared__ __align__(16) ushort KsH0[64 * 64], KsL0[64 * 64];
  __shared__ __align__(16) ushort VsH0[64 * 64], VsL0[64 * 64];
  __shared__ __align__(16) ushort KsH1[64 * 64], KsL1[64 * 64];
  __shared__ __align__(16) ushort VsH1[64 * 64], VsL1[64 * 64];

  const int t = threadIdx.x, lane = t & 63, w = t >> 6;
  const int fr = lane & 15, fg = lane >> 4;

  // XCD-aware decode: xcd owns bh in {4*xcd .. 4*xcd+3}, 16 q-blocks each
  const int bid = blockIdx.x;
  const int xcd = bid & 7, slot = bid >> 3;
  const int bh = xcd * 4 + (slot >> 4);
  const int q0 = (slot & 15) * 128;
  const int b = bh >> 4, h = bh & (HEADS - 1);

  // Q fragments from pre-split planes (linear)
  bfrag qh[2][2], ql[2][2];
#pragma unroll
  for (int qf = 0; qf < 2; qf++)
#pragma unroll
    for (int kk = 0; kk < 2; kk++) {
      size_t off = ((size_t)bh * SEQ + q0 + w * 32 + qf * 16 + fr) * 64 + kk * 32 + fg * 8;
      U4B uh, ul;
      uh.u = *(const uint4*)(Qh + off);
      ul.u = *(const uint4*)(Ql + off);
      qh[qf][kk] = uh.b;
      ql[qf][kk] = ul.b;
    }

  f32x4 Oacc[2][4];
#pragma unroll
  for (int qf = 0; qf < 2; qf++)
#pragma unroll
    for (int df = 0; df < 4; df++) Oacc[qf][df] = (f32x4){0.f, 0.f, 0.f, 0.f};
  float m_i[2] = {-1e30f, -1e30f}, l_i[2] = {0.f, 0.f};

  const int srcA = fr + ((fg & 1) << 5);   // (fallback path only)
  const int kisel = fg >> 1;

  // ---- STAGE: wave w loads one plane of the K-tile into given buffers ----
  auto STAGE = [&](ushort* KH, ushort* KL, ushort* VH, ushort* VL, int kt) {
    if (w < 2) {
      const ushort* p = w ? Kl : Kh;
      ushort* ld = w ? KL : KH;
#pragma unroll
      for (int i = 0; i < 8; i++) {
        const ushort* src = p + ((size_t)bh * SEQ + kt + i * 8 + (lane >> 3)) * 64 + ((lane & 7) << 3);
        gll16(src, &ld[i * 512]);
      }
    } else {
      const ushort* p = (w == 3) ? Vtl : Vth;
      ushort* ld = (w == 3) ? VL : VH;
#pragma unroll
      for (int i = 0; i < 8; i++) {
        const ushort* src = p + ((size_t)(bh * 64) + i * 8 + (lane >> 3)) * SEQ + kt + ((lane & 7) << 3);
        gll16(src, &ld[i * 512]);
      }
    }
  };

  // ---- COMPUTE: one 64-key tile from given buffers ----
  auto COMPUTE = [&](const ushort* KsH, const ushort* KsL,
                     const ushort* VsH, const ushort* VsL) {
    // QK^T swapped: sacc[ki][qf]: key = 16ki + 4fg + r, q = 16qf + fr
    f32x4 sacc[4][2];
#pragma unroll
    for (int ki = 0; ki < 4; ki++)
#pragma unroll
      for (int qf = 0; qf < 2; qf++) sacc[ki][qf] = (f32x4){0.f, 0.f, 0.f, 0.f};
#pragma unroll
    for (int kk = 0; kk < 2; kk++) {
#pragma unroll
      for (int ki = 0; ki < 4; ki++) {
        int r = ki * 16 + fr;
        int ad = r * 64 + (((kk * 4 + fg) ^ (r & 7)) << 3);
        bfrag kh = *(const bfrag*)&KsH[ad];
        bfrag kl = *(const bfrag*)&KsL[ad];
#pragma unroll
        for (int qf = 0; qf < 2; qf++) {
          sacc[ki][qf] = __builtin_amdgcn_mfma_f32_16x16x32_bf16(kh, qh[qf][kk], sacc[ki][qf], 0, 0, 0);
          sacc[ki][qf] = __builtin_amdgcn_mfma_f32_16x16x32_bf16(kh, ql[qf][kk], sacc[ki][qf], 0, 0, 0);
          sacc[ki][qf] = __builtin_amdgcn_mfma_f32_16x16x32_bf16(kl, qh[qf][kk], sacc[ki][qf], 0, 0, 0);
        }
      }
    }

#ifdef MFMA16
    bhalf4 paH[2][4], paL[2][4];   // [qf][ki] x16 A-frags (lane-local P)
#else
    unsigned phv[2][2][4], plv[2][2][4];   // [qf][pair][ki]
#endif
    // online softmax; lane's q = qf*16 + fr
#pragma unroll
    for (int qf = 0; qf < 2; qf++) {
      float mm = -1e30f;
#pragma unroll
      for (int ki = 0; ki < 4; ki++)
#pragma unroll
        for (int r = 0; r < 4; r++) mm = fmaxf(mm, sacc[ki][qf][r]);
      mm = fmaxf(mm, __shfl_xor(mm, 16));
      mm = fmaxf(mm, __shfl_xor(mm, 32));
      float mn = fmaxf(m_i[qf], mm);
      float alpha = __expf(m_i[qf] - mn);
      m_i[qf] = mn;
      float rs = 0.f;
      float pv[4][4];
#pragma unroll
      for (int ki = 0; ki < 4; ki++)
#pragma unroll
        for (int r = 0; r < 4; r++) {
          float p = __expf(sacc[ki][qf][r] - mn);
          pv[ki][r] = p;
          rs += p;
        }
      rs += __shfl_xor(rs, 16);
      rs += __shfl_xor(rs, 32);
      l_i[qf] = l_i[qf] * alpha + rs;
#ifdef MFMA16
#pragma unroll
      for (int ki = 0; ki < 4; ki++) {
        unsigned h0 = cvt_pk_bf16(pv[ki][0], pv[ki][1]);
        unsigned h1 = cvt_pk_bf16(pv[ki][2], pv[ki][3]);
        float e00 = __uint_as_float(h0 << 16), e01 = __uint_as_float(h0 & 0xFFFF0000u);
        float e10 = __uint_as_float(h1 << 16), e11 = __uint_as_float(h1 & 0xFFFF0000u);
        unsigned l0 = cvt_pk_bf16(pv[ki][0] - e00, pv[ki][1] - e01);
        unsigned l1 = cvt_pk_bf16(pv[ki][2] - e10, pv[ki][3] - e11);
        U2B th, tl;
        th.u = make_uint2(h0, h1);
        tl.u = make_uint2(l0, l1);
        paH[qf][ki] = th.b;
        paL[qf][ki] = tl.b;
      }
#else
#pragma unroll
      for (int ki = 0; ki < 4; ki++)
#pragma unroll
        for (int pr = 0; pr < 2; pr++) {
          float p0 = pv[ki][2 * pr], p1 = pv[ki][2 * pr + 1];
          unsigned hp = cvt_pk_bf16(p0, p1);
          float h0 = __uint_as_float(hp << 16);
          float h1 = __uint_as_float(hp & 0xFFFF0000u);
          phv[qf][pr][ki] = hp;
          plv[qf][pr][ki] = cvt_pk_bf16(p0 - h0, p1 - h1);
        }
#endif
      // rescale Oacc rows (their q = 16qf + 4fg + reg)
      float ar[4];
#pragma unroll
      for (int r = 0; r < 4; r++) ar[r] = __shfl(alpha, 4 * fg + r);
#pragma unroll
      for (int df = 0; df < 4; df++)
#pragma unroll
        for (int r = 0; r < 4; r++) Oacc[qf][df][r] *= ar[r];
    }

#ifdef MFMA16
    // PV via 16x16x16: A = own packed P (lane-local); B = Vt b64 reads
#pragma unroll
    for (int ki = 0; ki < 4; ki++) {
      bhalf4 vh[4], vl[4];
#pragma unroll
      for (int df = 0; df < 4; df++) {
        int d = df * 16 + fr;
        int ad = d * 64 + ((((2 * ki + (fg >> 1)) ^ (d & 7) ^ ((d >> 3) & 7))) << 3) + ((fg & 1) << 2);
        vh[df] = *(const bhalf4*)&VsH[ad];
        vl[df] = *(const bhalf4*)&VsL[ad];
      }
#pragma unroll
      for (int qf = 0; qf < 2; qf++)
#pragma unroll
        for (int df = 0; df < 4; df++) {
          Oacc[qf][df] = MFMA16(paH[qf][ki], vh[df], Oacc[qf][df]);
          Oacc[qf][df] = MFMA16(paH[qf][ki], vl[df], Oacc[qf][df]);
          Oacc[qf][df] = MFMA16(paL[qf][ki], vh[df], Oacc[qf][df]);
        }
    }
#else
    // Fallback PV via 16x16x32 + shfl regather of P fragments
#pragma unroll
    for (int kk = 0; kk < 2; kk++) {
      bfrag vh[4], vl[4];
#pragma unroll
      for (int df = 0; df < 4; df++) {
        int d = df * 16 + fr;
        int ad = d * 64 + (((kk * 4 + fg) ^ (d & 7) ^ ((d >> 3) & 7)) << 3);
        vh[df] = *(const bfrag*)&VsH[ad];
        vl[df] = *(const bfrag*)&VsL[ad];
      }
#pragma unroll
      for (int qf = 0; qf < 2; qf++) {
        U4B pah, pal;
#pragma unroll
        for (int wd = 0; wd < 4; wd++) {
          int src = srcA + ((wd >> 1) << 4);
          int pr = wd & 1;
          unsigned a0 = (unsigned)__shfl((int)phv[qf][pr][2 * kk], src);
          unsigned a1 = (unsigned)__shfl((int)phv[qf][pr][2 * kk + 1], src);
          unsigned b0 = (unsigned)__shfl((int)plv[qf][pr][2 * kk], src);
          unsigned b1 = (unsigned)__shfl((int)plv[qf][pr][2 * kk + 1], src);
          (&pah.u.x)[wd] = kisel ? a1 : a0;
          (&pal.u.x)[wd] = kisel ? b1 : b0;
        }
#pragma unroll
        for (int df = 0; df < 4; df++) {
          Oacc[qf][df] = __builtin_amdgcn_mfma_f32_16x16x32_bf16(pah.b, vh[df], Oacc[qf][df], 0, 0, 0);
          Oacc[qf][df] = __builtin_amdgcn_mfma_f32_16x16x32_bf16(pah.b, vl[df], Oacc[qf][df], 0, 0, 0);
          Oacc[qf][df] = __builtin_amdgcn_mfma_f32_16x16x32_bf16(pal.b, vh[df], Oacc[qf][df], 0, 0, 0);
        }
      }
    }
#endif
  };

  // ---- 2-phase double-buffered main loop (static buffer names) ----
  STAGE(KsH0, KsL0, VsH0, VsL0, 0);
  __syncthreads();
  for (int kt = 0; kt < SEQ; kt += 128) {
    STAGE(KsH1, KsL1, VsH1, VsL1, kt + 64);
    COMPUTE(KsH0, KsL0, VsH0, VsL0);
    __syncthreads();
    if (kt + 128 < SEQ) STAGE(KsH0, KsL0, VsH0, VsL0, kt + 128);
    COMPUTE(KsH1, KsL1, VsH1, VsL1);
    __syncthreads();
  }

  // epilogue: Ab[m][1024], m = b*SEQ+s, col = h*64+d
#pragma unroll
  for (int qf = 0; qf < 2; qf++) {
    float lr[4];
#pragma unroll
    for (int r = 0; r < 4; r++) lr[r] = 1.0f / __shfl(l_i[qf], 4 * fg + r);
#pragma unroll
    for (int df = 0; df < 4; df++)
#pragma unroll
      for (int r = 0; r < 4; r++) {
        int s = q0 + w * 32 + qf * 16 + 4 * fg + r;
        int d = df * 16 + fr;
        Ab[((size_t)(b * SEQ + s)) * 1024 + h * 64 + d] = Oacc[qf][df][r] * lr[r];
      }
  }
}

extern "C" void kernel_launch(void* const* d_in, const int* in_sizes, int n_in,
                              void* d_out, int out_size, void* d_ws, size_t ws_size,
                              hipStream_t stream) {
  const float* x    = (const float*)d_in[0];
  const float* Wqkv = (const float*)d_in[1];
  const float* bqkv = (const float*)d_in[2];
  const float* Wout = (const float*)d_in[3];
  const float* bout = (const float*)d_in[4];
  float* out = (float*)d_out;

  char* W = (char*)d_ws;
  float* ctab = (float*)W;  W += (size_t)SEQ * 32 * 4;
  float* stab = (float*)W;  W += (size_t)SEQ * 32 * 4;
  float* Qb   = (float*)W;  W += (size_t)16 << 20;   // alias: Abf after rope
  float* Kb   = (float*)W;  W += (size_t)16 << 20;   // alias: abh+abl after rope
  float* Vb   = (float*)W;  W += (size_t)16 << 20;
  ushort* xh  = (ushort*)W; W += (size_t)8 << 20;    // alias: Qhp after gemm1
  ushort* xl  = (ushort*)W; W += (size_t)8 << 20;    // alias: Qlp after gemm1
  ushort* wqh = (ushort*)W; W += (size_t)6 << 20;
  ushort* wql = (ushort*)W; W += (size_t)6 << 20;
  ushort* woh = (ushort*)W; W += (size_t)2 << 20;
  ushort* wol = (ushort*)W; W += (size_t)2 << 20;
  ushort* Khp = (ushort*)W; W += (size_t)8 << 20;
  ushort* Klp = (ushort*)W; W += (size_t)8 << 20;
  ushort* Vthp = (ushort*)W; W += (size_t)8 << 20;
  ushort* Vtlp = (ushort*)W; W += (size_t)8 << 20;
  ushort* Qhp = xh;                   // xh/xl dead after gemm1
  ushort* Qlp = xl;
  float* Abf = Qb;                    // Qb fp32 dead after rope_split
  ushort* abh = (ushort*)Kb;          // Kb fp32 dead after rope_split
  ushort* abl = abh + ((size_t)4 << 20);

  hipLaunchKernelGGL(rope_table_k, dim3(SEQ * 32 / 256), dim3(256), 0, stream, ctab, stab);
  hipLaunchKernelGGL(split_swz4, dim3(4096 / 2), dim3(256), 0, stream, x, xh, xl);
  hipLaunchKernelGGL(split_swz4, dim3(3072 / 2), dim3(256), 0, stream, Wqkv, wqh, wql);
  hipLaunchKernelGGL(split_swz4, dim3(1024 / 2), dim3(256), 0, stream, Wout, woh, wol);
  hipLaunchKernelGGL(gemm32, dim3(768), dim3(256), 0, stream,
                     xh, xl, wqh, wql, bqkv, (float*)nullptr, Qb, Kb, Vb, 3072, 1);
  hipLaunchKernelGGL(rope_split_k, dim3(BATCH * HEADS * SEQ * 4 / 256, 2), dim3(256), 0, stream,
                     Qb, Kb, ctab, stab, Qhp, Qlp, Khp, Klp);
  hipLaunchKernelGGL(vtrans_split, dim3(SEQ / 64, BATCH * HEADS), dim3(256), 0, stream,
                     Vb, Vthp, Vtlp);
  hipLaunchKernelGGL(attn_mfma2, dim3(512), dim3(256), 0, stream,
                     Qhp, Qlp, Khp, Klp, Vthp, Vtlp, Abf);
  hipLaunchKernelGGL(split_swz4, dim3(4096 / 2), dim3(256), 0, stream, Abf, abh, abl);
  hipLaunchKernelGGL(gemm32, dim3(256), dim3(256), 0, stream,
                     abh, abl, woh, wol, bout, out,
                     (float*)nullptr, (float*)nullptr, (float*)nullptr, 1024, 0);
}